// Round 5
// baseline (473.726 us; speedup 1.0000x reference)
//
#include <hip/hip_runtime.h>

// Biquad DF2T over [B=512, T=48000] fp32, per-channel coeffs.
// SINGLE-PASS decoupled-lookback scan (replaces round-4's two-dispatch
// design, which doubled x reads and duplicated the local scan):
//   grid = 4096 blocks = 8 chunks/channel x 512 channels, CHUNK-MAJOR
//   (bid = c*512 + b) so all of a chunk's predecessors have smaller bid.
//   Per block (512 thr, 500 active, 12 samples/thread in 3 float4 regs):
//     1) per-thread-row loads -> registers
//     2) zero-state response + 6-round __shfl_up Kogge-Stone (no barriers)
//     3) barrier A; t0 composes 8 wave aggs -> block aggregate,
//        publishes it (agent release), then LOOKBACK over <=7 predecessor
//        records (inclusive record short-circuits the walk), publishes own
//        inclusive state, drops entry state in LDS
//     4) barrier B; all threads fold wave aggs + entry -> own init state
//     5) replay exact reference arithmetic -> LDS rows; barrier C
//     6) LDS transpose -> nontemporal coalesced float4 stores
// ws flags are zeroed in-stream (hipMemsetAsync) every launch so stale
// status words from a prior timed iteration can never short-circuit waits.
// Payload goes through agent-scope atomics (cross-XCD L2 non-coherence).
// Progress: resident capacity ~4 blocks/CU = 1024 blocks >= 2 chunk
// generations; chunk-major ordering + in-blockIdx-order dispatch gives
// forward progress (rocPRIM decoupled-lookback relies on the same).

#define B_CH   512
#define T_LEN  48000
#define CPC    8            // chunks per channel
#define CHUNK  6000         // samples per chunk
#define NBLK   (B_CH * CPC) // 4096
#define NACT   500          // active threads per block
#define L      12           // samples per thread
#define NF4R   3            // float4 per thread row
#define STRIDE 13           // padded LDS row stride (floats)
#define NF4C   (CHUNK / 4)  // 1500 float4 per chunk
#define NWAVE  8
#define WSROW  16           // floats per chunk record (64 B)
// record: [0..3]=P  [4..5]=w  [6..7]=inclusive z  [15]=status (0/1/2)

typedef float f4_t __attribute__((ext_vector_type(4)));

__device__ __forceinline__ void barrier_lds()
{
    asm volatile("s_waitcnt lgkmcnt(0)" ::: "memory");
    __builtin_amdgcn_s_barrier();
}

__device__ __forceinline__ float aload(const float* p)
{
    return __hip_atomic_load(p, __ATOMIC_RELAXED, __HIP_MEMORY_SCOPE_AGENT);
}
__device__ __forceinline__ void astore(float* p, float v)
{
    __hip_atomic_store(p, v, __ATOMIC_RELAXED, __HIP_MEMORY_SCOPE_AGENT);
}

// G = A^L, A = [[-a1,1],[-a2,0]] (binary exponentiation)
__device__ __forceinline__ void mat_pow(float A1, float A2,
                                        float& G00, float& G01,
                                        float& G10, float& G11)
{
    float m00 = -A1, m01 = 1.f, m10 = -A2, m11 = 0.f;
    float f00 = 1.f, f01 = 0.f, f10 = 0.f, f11 = 1.f;
    int e = L;
    while (e) {
        if (e & 1) {
            const float t00 = f00*m00 + f01*m10, t01 = f00*m01 + f01*m11;
            const float t10 = f10*m00 + f11*m10, t11 = f10*m01 + f11*m11;
            f00 = t00; f01 = t01; f10 = t10; f11 = t11;
        }
        e >>= 1;
        if (!e) break;
        const float s00 = m00*m00 + m01*m10, s01 = m00*m01 + m01*m11;
        const float s10 = m10*m00 + m11*m10, s11 = m10*m01 + m11*m11;
        m00 = s00; m01 = s01; m10 = s10; m11 = s11;
    }
    G00 = f00; G01 = f01; G10 = f10; G11 = f11;
}

__global__ __launch_bounds__(512, 4) void k_biquad_lb(
    const float* __restrict__ x,
    const float* __restrict__ b0v, const float* __restrict__ b1v,
    const float* __restrict__ b2v,
    const float* __restrict__ a1v, const float* __restrict__ a2v,
    float* __restrict__ ws,
    float* __restrict__ y)
{
    __shared__ float xl[NACT * STRIDE];   // 6500 floats = 26 KB (y transpose)
    __shared__ float aggP[NWAVE][4];
    __shared__ float aggW[NWAVE][2];
    __shared__ float entry[2];

    const int bid  = blockIdx.x;
    const int c    = bid >> 9;        // chunk index 0..7 (chunk-major)
    const int b    = bid & 511;       // channel
    const int t    = threadIdx.x;
    const int lane = t & 63;
    const int wid  = t >> 6;

    const float A1 = a1v[b], A2 = a2v[b];
    const float B0 = b0v[b], B1 = b1v[b], B2 = b2v[b];
    const float c1 = B1 - A1 * B0;
    const float c2 = B2 - A2 * B0;

    float G00, G01, G10, G11;
    mat_pow(A1, A2, G00, G01, G10, G11);

    // ---- per-thread-row loads -> registers (issued early)
    f4_t xr[NF4R];
    if (t < NACT) {
        const f4_t* p = (const f4_t*)(x + (size_t)b * T_LEN + c * CHUNK + t * L);
        xr[0] = p[0]; xr[1] = p[1]; xr[2] = p[2];
    }

    // ---- local zero-state response (y-eliminated form, registers only)
    float P00, P01, P10, P11, w0, w1;
    if (t < NACT) {
        float z1 = 0.f, z2 = 0.f;
        #pragma unroll
        for (int k = 0; k < NF4R; ++k) {
            const f4_t v = xr[k];
            { const float xn = v.x; const float n1 = c1*xn + z2 - A1*z1; z2 = c2*xn - A2*z1; z1 = n1; }
            { const float xn = v.y; const float n1 = c1*xn + z2 - A1*z1; z2 = c2*xn - A2*z1; z1 = n1; }
            { const float xn = v.z; const float n1 = c1*xn + z2 - A1*z1; z2 = c2*xn - A2*z1; z1 = n1; }
            { const float xn = v.w; const float n1 = c1*xn + z2 - A1*z1; z2 = c2*xn - A2*z1; z1 = n1; }
        }
        P00 = G00; P01 = G01; P10 = G10; P11 = G11; w0 = z1; w1 = z2;
    } else {
        P00 = 1.f; P01 = 0.f; P10 = 0.f; P11 = 1.f; w0 = 0.f; w1 = 0.f;
    }

    // ---- intra-wave inclusive Kogge-Stone via shuffles (no barriers)
    #pragma unroll
    for (int off = 1; off < 64; off <<= 1) {
        const float e00 = __shfl_up(P00, off);
        const float e01 = __shfl_up(P01, off);
        const float e10 = __shfl_up(P10, off);
        const float e11 = __shfl_up(P11, off);
        const float u0  = __shfl_up(w0,  off);
        const float u1  = __shfl_up(w1,  off);
        if (lane >= off) {
            const float n00 = P00*e00 + P01*e10, n01 = P00*e01 + P01*e11;
            const float n10 = P10*e00 + P11*e10, n11 = P10*e01 + P11*e11;
            w0 = P00*u0 + P01*u1 + w0;
            w1 = P10*u0 + P11*u1 + w1;
            P00 = n00; P01 = n01; P10 = n10; P11 = n11;
        }
    }

    if (lane == 63) {
        aggP[wid][0] = P00; aggP[wid][1] = P01;
        aggP[wid][2] = P10; aggP[wid][3] = P11;
        aggW[wid][0] = w0;  aggW[wid][1] = w1;
    }

    // exclusive-within-wave = inclusive shifted down one lane
    float E00 = __shfl_up(P00, 1), E01 = __shfl_up(P01, 1);
    float E10 = __shfl_up(P10, 1), E11 = __shfl_up(P11, 1);
    float Ew0 = __shfl_up(w0, 1),  Ew1 = __shfl_up(w1, 1);
    if (lane == 0) { E00 = 1.f; E01 = 0.f; E10 = 0.f; E11 = 1.f; Ew0 = 0.f; Ew1 = 0.f; }

    barrier_lds();   // A: wave aggregates visible

    // ---- t0: compose block aggregate, publish, lookback, publish inclusive
    if (t == 0) {
        float p00 = 1.f, p01 = 0.f, p10 = 0.f, p11 = 1.f, q0 = 0.f, q1 = 0.f;
        #pragma unroll
        for (int k = 0; k < NWAVE; ++k) {   // F := E_k . F (time order)
            const float e00 = aggP[k][0], e01 = aggP[k][1];
            const float e10 = aggP[k][2], e11 = aggP[k][3];
            const float s0  = aggW[k][0], s1  = aggW[k][1];
            const float n00 = e00*p00 + e01*p10, n01 = e00*p01 + e01*p11;
            const float n10 = e10*p00 + e11*p10, n11 = e10*p01 + e11*p11;
            const float nw0 = e00*q0 + e01*q1 + s0;
            const float nw1 = e10*q0 + e11*q1 + s1;
            p00 = n00; p01 = n01; p10 = n10; p11 = n11; q0 = nw0; q1 = nw1;
        }

        float* row = ws + (size_t)bid * WSROW;
        float e0 = 0.f, e1 = 0.f;   // state entering this chunk

        if (c == 0) {
            // entry is zero: publish inclusive directly
            astore(row + 6, q0);
            astore(row + 7, q1);
            __hip_atomic_store((unsigned*)(row + 15), 2u,
                               __ATOMIC_RELEASE, __HIP_MEMORY_SCOPE_AGENT);
        } else {
            // publish aggregate first so successors can make progress
            astore(row + 0, p00); astore(row + 1, p01);
            astore(row + 2, p10); astore(row + 3, p11);
            astore(row + 4, q0);  astore(row + 5, q1);
            __hip_atomic_store((unsigned*)(row + 15), 1u,
                               __ATOMIC_RELEASE, __HIP_MEMORY_SCOPE_AGENT);

            // lookback: maintain affine (R, v): entry_c = R * s_{p+1} + v
            float R00 = 1.f, R01 = 0.f, R10 = 0.f, R11 = 1.f, v0 = 0.f, v1 = 0.f;
            int p = c - 1;
            for (;;) {
                const float* prow = ws + (size_t)(((p << 9) | b)) * WSROW;
                unsigned st;
                for (;;) {
                    st = __hip_atomic_load((const unsigned*)(prow + 15),
                                           __ATOMIC_ACQUIRE, __HIP_MEMORY_SCOPE_AGENT);
                    if (st) break;
                    __builtin_amdgcn_s_sleep(2);
                }
                if (st == 2u) {                 // inclusive: done
                    const float i0 = aload(prow + 6), i1 = aload(prow + 7);
                    e0 = R00*i0 + R01*i1 + v0;
                    e1 = R10*i0 + R11*i1 + v1;
                    break;
                } else {                        // aggregate: fold, keep walking
                    const float a0 = aload(prow + 0), a1_ = aload(prow + 1);
                    const float a2_ = aload(prow + 2), a3 = aload(prow + 3);
                    const float u0 = aload(prow + 4), u1 = aload(prow + 5);
                    const float n00 = R00*a0 + R01*a2_, n01 = R00*a1_ + R01*a3;
                    const float n10 = R10*a0 + R11*a2_, n11 = R10*a1_ + R11*a3;
                    v0 = R00*u0 + R01*u1 + v0;
                    v1 = R10*u0 + R11*u1 + v1;
                    R00 = n00; R01 = n01; R10 = n10; R11 = n11;
                    if (--p < 0) { e0 = v0; e1 = v1; break; }  // s_0 = 0
                }
            }

            if (c + 1 < CPC) {
                astore(row + 6, p00*e0 + p01*e1 + q0);
                astore(row + 7, p10*e0 + p11*e1 + q1);
                __hip_atomic_store((unsigned*)(row + 15), 2u,
                                   __ATOMIC_RELEASE, __HIP_MEMORY_SCOPE_AGENT);
            }
        }
        entry[0] = e0; entry[1] = e1;
    }

    barrier_lds();   // B: entry state visible

    const float cz1 = entry[0], cz2 = entry[1];

    // ---- carry-aware fold of wave aggregates (wave-uniform broadcasts)
    float s0 = cz1, s1 = cz2, my0 = cz1, my1 = cz2;
    #pragma unroll
    for (int k = 0; k < NWAVE; ++k) {
        if (k == wid) { my0 = s0; my1 = s1; }
        const float p0 = aggP[k][0], p1 = aggP[k][1];
        const float p2 = aggP[k][2], p3 = aggP[k][3];
        const float q0 = aggW[k][0], q1 = aggW[k][1];
        const float n0 = p0*s0 + p1*s1 + q0;
        const float n1 = p2*s0 + p3*s1 + q1;
        s0 = n0; s1 = n1;
    }

    // this thread's true initial state
    float z1 = E00*my0 + E01*my1 + Ew0;
    float z2 = E10*my0 + E11*my1 + Ew1;

    // ---- replay with exact reference arithmetic: registers -> LDS rows
    if (t < NACT) {
        float* r = &xl[t * STRIDE];
        #pragma unroll
        for (int k = 0; k < NF4R; ++k) {
            const f4_t v = xr[k];
            { const float xn = v.x; const float yn = B0*xn + z1; r[4*k+0] = yn;
              const float n1 = B1*xn - A1*yn + z2; z2 = B2*xn - A2*yn; z1 = n1; }
            { const float xn = v.y; const float yn = B0*xn + z1; r[4*k+1] = yn;
              const float n1 = B1*xn - A1*yn + z2; z2 = B2*xn - A2*yn; z1 = n1; }
            { const float xn = v.z; const float yn = B0*xn + z1; r[4*k+2] = yn;
              const float n1 = B1*xn - A1*yn + z2; z2 = B2*xn - A2*yn; z1 = n1; }
            { const float xn = v.w; const float yn = B0*xn + z1; r[4*k+3] = yn;
              const float n1 = B1*xn - A1*yn + z2; z2 = B2*xn - A2*yn; z1 = n1; }
        }
    }
    barrier_lds();   // C: y rows complete

    // ---- writeback: LDS rows -> nontemporal coalesced float4 stores
    float* ys = y + (size_t)b * T_LEN + c * CHUNK;
    #pragma unroll
    for (int k = 0; k < NF4R; ++k) {
        const int g = t + 512 * k;
        if (g < NF4C) {
            const int own = g / 3;
            const int off = (g - 3 * own) * 4;
            const float* sp = &xl[own * STRIDE + off];
            f4_t v;
            v.x = sp[0]; v.y = sp[1]; v.z = sp[2]; v.w = sp[3];
            __builtin_nontemporal_store(v, (f4_t*)(ys + 4 * g));
        }
    }
}

extern "C" void kernel_launch(void* const* d_in, const int* in_sizes, int n_in,
                              void* d_out, int out_size, void* d_ws, size_t ws_size,
                              hipStream_t stream) {
    const float* x  = (const float*)d_in[0];
    const float* b0 = (const float*)d_in[1];
    const float* b1 = (const float*)d_in[2];
    const float* b2 = (const float*)d_in[3];
    const float* a1 = (const float*)d_in[4];
    const float* a2 = (const float*)d_in[5];
    float* y  = (float*)d_out;
    float* ws = (float*)d_ws;   // 4096 * 16 floats = 256 KB

    // zero status/flag records every launch (stale status=2 from a prior
    // timed iteration would short-circuit the lookback)
    hipMemsetAsync(ws, 0, (size_t)NBLK * WSROW * sizeof(float), stream);

    k_biquad_lb<<<dim3(NBLK), dim3(512), 0, stream>>>(x, b0, b1, b2, a1, a2, ws, y);
}

// Round 6
// 221.248 us; speedup vs baseline: 2.1412x; 2.1412x over previous
//
#include <hip/hip_runtime.h>

// Biquad DF2T over [B=512, T=48000] fp32, per-channel coeffs.
// One block per channel, 512 threads, 3 stages of 16000 samples.
// FULLY REGISTER-RESIDENT: x and y never touch LDS; per thread per stage
// a 32-sample row = 8 float4 = exactly two aligned 64B lines (full-line
// loads AND stores, no transpose needed). LDS holds only 3x8 wave
// aggregates (576 B), one buffer per stage so there is no WAR hazard.
// ONE barrier per stage (3 total), built without a "memory" clobber so
// the compiler does NOT drain vmcnt at it -- prior rounds' barriers all
// forced full store/load drains (the suspected 66us floor).
// Load/store issue order per wave keeps vmcnt monotone: stage s+1 loads
// are issued BEFORE stage s stores, so consuming the loads waits
// vmcnt(8) and never drains the stores.

#define B_CH   512
#define T_LEN  48000
#define NSTAGE 3
#define STAGE  16000        // samples per stage (NACT * L)
#define NACT   500          // active compute threads
#define L      32           // samples per thread per stage (128 B row)
#define NF4R   8            // float4 per thread row
#define NWAVE  8

typedef float f4_t __attribute__((ext_vector_type(4)));

// Barrier that waits only LDS (lgkmcnt), leaves global loads/stores in
// flight. No "memory" clobber => no conservative vmcnt(0) insertion.
// sched_barrier(0) pins compiler motion (guide rule #18); volatile LDS
// accesses order themselves against the asm volatile at IR level.
__device__ __forceinline__ void barrier_nodrain()
{
    __builtin_amdgcn_sched_barrier(0);
    asm volatile("s_waitcnt lgkmcnt(0)");
    __builtin_amdgcn_s_barrier();
    __builtin_amdgcn_sched_barrier(0);
}

// G = A^L, A = [[-a1,1],[-a2,0]] (binary exponentiation)
__device__ __forceinline__ void mat_pow(float A1, float A2,
                                        float& G00, float& G01,
                                        float& G10, float& G11)
{
    float m00 = -A1, m01 = 1.f, m10 = -A2, m11 = 0.f;
    float f00 = 1.f, f01 = 0.f, f10 = 0.f, f11 = 1.f;
    int e = L;
    while (e) {
        if (e & 1) {
            const float t00 = f00*m00 + f01*m10, t01 = f00*m01 + f01*m11;
            const float t10 = f10*m00 + f11*m10, t11 = f10*m01 + f11*m11;
            f00 = t00; f01 = t01; f10 = t10; f11 = t11;
        }
        e >>= 1;
        if (!e) break;
        const float s00 = m00*m00 + m01*m10, s01 = m00*m01 + m01*m11;
        const float s10 = m10*m00 + m11*m10, s11 = m10*m01 + m11*m11;
        m00 = s00; m01 = s01; m10 = s10; m11 = s11;
    }
    G00 = f00; G01 = f01; G10 = f10; G11 = f11;
}

__global__ __launch_bounds__(512, 4) void k_biquad_reg(
    const float* __restrict__ x,
    const float* __restrict__ b0v, const float* __restrict__ b1v,
    const float* __restrict__ b2v,
    const float* __restrict__ a1v, const float* __restrict__ a2v,
    float* __restrict__ y)
{
    // per-stage aggregate buffers: no WAR hazard across stages
    __shared__ volatile float aggP[NSTAGE][NWAVE][4];
    __shared__ volatile float aggW[NSTAGE][NWAVE][2];

    const int b    = blockIdx.x;
    const int t    = threadIdx.x;
    const int lane = t & 63;
    const int wid  = t >> 6;

    const float A1 = a1v[b], A2 = a2v[b];
    const float B0 = b0v[b], B1 = b1v[b], B2 = b2v[b];
    // y-eliminated state form: z1' = c1*x - a1*z1 + z2 ; z2' = c2*x - a2*z1
    const float c1 = B1 - A1 * B0;
    const float c2 = B2 - A2 * B0;

    float G00, G01, G10, G11;
    mat_pow(A1, A2, G00, G01, G10, G11);

    const float* __restrict__ xb = x + (size_t)b * T_LEN;
    float*       __restrict__ yb = y + (size_t)b * T_LEN;

    float cz1 = 0.f, cz2 = 0.f;   // inter-stage carry state

    auto do_stage = [&](int s, f4_t (&cur)[NF4R], f4_t (&nxt)[NF4R]) {
        // ---- issue next-stage row loads FIRST (before this stage's
        //      stores) so waiting for them later is vmcnt(8), not 0
        if (s + 1 < NSTAGE && t < NACT) {
            const f4_t* p = (const f4_t*)(xb + (s + 1) * STAGE + t * L);
            #pragma unroll
            for (int k = 0; k < NF4R; ++k) nxt[k] = p[k];
        }

        // ---- local zero-state response (registers only)
        float P00, P01, P10, P11, w0, w1;
        if (t < NACT) {
            float z1 = 0.f, z2 = 0.f;
            #pragma unroll
            for (int k = 0; k < NF4R; ++k) {
                const f4_t v = cur[k];
                { const float xn = v.x; const float n1 = c1*xn + z2 - A1*z1; z2 = c2*xn - A2*z1; z1 = n1; }
                { const float xn = v.y; const float n1 = c1*xn + z2 - A1*z1; z2 = c2*xn - A2*z1; z1 = n1; }
                { const float xn = v.z; const float n1 = c1*xn + z2 - A1*z1; z2 = c2*xn - A2*z1; z1 = n1; }
                { const float xn = v.w; const float n1 = c1*xn + z2 - A1*z1; z2 = c2*xn - A2*z1; z1 = n1; }
            }
            P00 = G00; P01 = G01; P10 = G10; P11 = G11; w0 = z1; w1 = z2;
        } else {
            P00 = 1.f; P01 = 0.f; P10 = 0.f; P11 = 1.f; w0 = 0.f; w1 = 0.f;
        }

        // ---- intra-wave inclusive Kogge-Stone via shuffles (no barriers)
        #pragma unroll
        for (int off = 1; off < 64; off <<= 1) {
            const float e00 = __shfl_up(P00, off);
            const float e01 = __shfl_up(P01, off);
            const float e10 = __shfl_up(P10, off);
            const float e11 = __shfl_up(P11, off);
            const float u0  = __shfl_up(w0,  off);
            const float u1  = __shfl_up(w1,  off);
            if (lane >= off) {
                const float n00 = P00*e00 + P01*e10, n01 = P00*e01 + P01*e11;
                const float n10 = P10*e00 + P11*e10, n11 = P10*e01 + P11*e11;
                w0 = P00*u0 + P01*u1 + w0;
                w1 = P10*u0 + P11*u1 + w1;
                P00 = n00; P01 = n01; P10 = n10; P11 = n11;
            }
        }

        // publish wave aggregates (lane 63 inclusive = whole-wave transform)
        if (lane == 63) {
            aggP[s][wid][0] = P00; aggP[s][wid][1] = P01;
            aggP[s][wid][2] = P10; aggP[s][wid][3] = P11;
            aggW[s][wid][0] = w0;  aggW[s][wid][1] = w1;
        }

        // exclusive-within-wave = inclusive shifted down one lane
        float E00 = __shfl_up(P00, 1), E01 = __shfl_up(P01, 1);
        float E10 = __shfl_up(P10, 1), E11 = __shfl_up(P11, 1);
        float Ew0 = __shfl_up(w0, 1),  Ew1 = __shfl_up(w1, 1);
        if (lane == 0) { E00 = 1.f; E01 = 0.f; E10 = 0.f; E11 = 1.f; Ew0 = 0.f; Ew1 = 0.f; }

        barrier_nodrain();   // the ONLY barrier in the stage

        // ---- carry-aware fold of wave aggregates (wave-uniform)
        float s0 = cz1, s1 = cz2, my0 = cz1, my1 = cz2;
        #pragma unroll
        for (int k = 0; k < NWAVE; ++k) {
            if (k == wid) { my0 = s0; my1 = s1; }
            const float p0 = aggP[s][k][0], p1 = aggP[s][k][1];
            const float p2 = aggP[s][k][2], p3 = aggP[s][k][3];
            const float q0 = aggW[s][k][0], q1 = aggW[s][k][1];
            const float n0 = p0*s0 + p1*s1 + q0;
            const float n1 = p2*s0 + p3*s1 + q1;
            s0 = n0; s1 = n1;
        }
        cz1 = s0; cz2 = s1;   // carry advanced past this stage

        // this thread's true initial state
        float z1 = E00*my0 + E01*my1 + Ew0;
        float z2 = E10*my0 + E11*my1 + Ew1;

        // ---- replay with exact reference arithmetic; direct full-line
        //      dwordx4 stores (row = 2 aligned 64B lines). Fire-and-forget.
        if (t < NACT) {
            f4_t* q = (f4_t*)(yb + s * STAGE + t * L);
            #pragma unroll
            for (int k = 0; k < NF4R; ++k) {
                const f4_t v = cur[k];
                f4_t o;
                { const float xn = v.x; const float yn = B0*xn + z1; o.x = yn;
                  const float n1 = B1*xn - A1*yn + z2; z2 = B2*xn - A2*yn; z1 = n1; }
                { const float xn = v.y; const float yn = B0*xn + z1; o.y = yn;
                  const float n1 = B1*xn - A1*yn + z2; z2 = B2*xn - A2*yn; z1 = n1; }
                { const float xn = v.z; const float yn = B0*xn + z1; o.z = yn;
                  const float n1 = B1*xn - A1*yn + z2; z2 = B2*xn - A2*yn; z1 = n1; }
                { const float xn = v.w; const float yn = B0*xn + z1; o.w = yn;
                  const float n1 = B1*xn - A1*yn + z2; z2 = B2*xn - A2*yn; z1 = n1; }
                q[k] = o;
            }
        }
    };

    // ---- prologue: load stage-0 rows into registers
    f4_t bufA[NF4R], bufB[NF4R];
    if (t < NACT) {
        const f4_t* p = (const f4_t*)(xb + t * L);
        #pragma unroll
        for (int k = 0; k < NF4R; ++k) bufA[k] = p[k];
    }

    // ping-pong with compile-time-constant buffer naming
    do_stage(0, bufA, bufB);
    do_stage(1, bufB, bufA);
    do_stage(2, bufA, bufB);
}

extern "C" void kernel_launch(void* const* d_in, const int* in_sizes, int n_in,
                              void* d_out, int out_size, void* d_ws, size_t ws_size,
                              hipStream_t stream) {
    const float* x  = (const float*)d_in[0];
    const float* b0 = (const float*)d_in[1];
    const float* b1 = (const float*)d_in[2];
    const float* b2 = (const float*)d_in[3];
    const float* a1 = (const float*)d_in[4];
    const float* a2 = (const float*)d_in[5];
    float* y = (float*)d_out;

    k_biquad_reg<<<dim3(B_CH), dim3(512), 0, stream>>>(x, b0, b1, b2, a1, a2, y);
}